// Round 4
// baseline (464.427 us; speedup 1.0000x reference)
//
#include <hip/hip_runtime.h>
#include <stdint.h>

#define N_NODES 2048
#define DIM 1024
#define BATCH 16384
#define NEDGE 65536
#define CAP 96

typedef __bf16 bf16x8 __attribute__((ext_vector_type(8)));
typedef float f32x4 __attribute__((ext_vector_type(4)));
typedef unsigned short u16;
typedef unsigned int u32;

__device__ __forceinline__ u16 f2bf(float f) {
  union { float f; u32 i; } v; v.f = f;
  u32 r = v.i + 0x7fffu + ((v.i >> 16) & 1u);
  return (u16)(r >> 16);
}

// ---------- detect int64-vs-int32 index array ----------
__global__ void k_detect(const int* __restrict__ dx, int* __restrict__ flag) {
  if (threadIdx.x == 0 && blockIdx.x == 0) {
    int is64 = 1;
    for (int j = 0; j < 32; ++j)
      if (dx[2 * j + 1] != 0) { is64 = 0; break; }
    *flag = is64;
  }
}

__global__ __launch_bounds__(256) void k_cvt(const int* __restrict__ dx,
                                             const int* __restrict__ flag,
                                             int* __restrict__ idx) {
  int i = blockIdx.x * 256 + threadIdx.x;
  if (i >= 7 * BATCH) return;
  int v = (*flag) ? dx[2 * i] : dx[i];
  idx[i] = v & (N_NODES - 1);
}

// ---------- stage 1: bucket fill ----------
__global__ __launch_bounds__(256) void k_bucket(const int* __restrict__ idx,
                                                int* __restrict__ counts,
                                                int* __restrict__ bucket) {
  int i = blockIdx.x * 256 + threadIdx.x;
  if (i >= 2 * BATCH) return;
  int n = (i < BATCH) ? idx[7 * i] : idx[7 * (i - BATCH) + 1];
  int slot = atomicAdd(&counts[n], 1);
  if (slot < CAP) bucket[n * CAP + slot] = i;
}

// ---------- stage 2: per-node segment sum (f32 in) -> A1 (bf16) ----------
__global__ __launch_bounds__(256) void k_nodesum(const float* __restrict__ feat,
                                                 const int* __restrict__ counts,
                                                 const int* __restrict__ bucket,
                                                 u16* __restrict__ A1) {
  int n = blockIdx.x;
  int tid = threadIdx.x;
  int cnt = counts[n]; if (cnt > CAP) cnt = CAP;
  float a0 = 0.f, a1 = 0.f, a2 = 0.f, a3 = 0.f;
  for (int j = 0; j < cnt; ++j) {
    int i = bucket[n * CAP + j];
    size_t rowoff = (i < BATCH) ? ((size_t)i * 7) * DIM
                                : ((size_t)(i - BATCH) * 7 + 1) * DIM;
    f32x4 v = *(const f32x4*)(feat + rowoff + tid * 4);
    a0 += v[0]; a1 += v[1]; a2 += v[2]; a3 += v[3];
  }
  ushort4 o; o.x = f2bf(a0); o.y = f2bf(a1); o.z = f2bf(a2); o.w = f2bf(a3);
  *(ushort4*)(A1 + (size_t)n * DIM + tid * 4) = o;
}

// ---------- weight transpose (K x N, f32) -> (N x K, bf16) ----------
__global__ __launch_bounds__(256) void k_transpose(const float* __restrict__ W,
                                                   u16* __restrict__ Wt,
                                                   int K, int N) {
  __shared__ __align__(16) u16 t[32][33];
  int ntx = N >> 5;
  int bx = blockIdx.x % ntx;
  int by = blockIdx.x / ntx;
  int tx = threadIdx.x & 31, ty = threadIdx.x >> 5;  // 32 x 8
  #pragma unroll
  for (int r = 0; r < 32; r += 8)
    t[r + ty][tx] = f2bf(W[(size_t)(by * 32 + r + ty) * N + bx * 32 + tx]);
  __syncthreads();
  #pragma unroll
  for (int r = 0; r < 32; r += 8)
    Wt[(size_t)(bx * 32 + r + ty) * K + by * 32 + tx] = t[tx][r + ty];
}

// ---------- CSR row_ptr via binary search over sorted adj_rows ----------
__global__ __launch_bounds__(256) void k_rowptr(const int* __restrict__ adj_rows,
                                                int* __restrict__ row_ptr) {
  int r = blockIdx.x * 256 + threadIdx.x;
  if (r > N_NODES) return;
  int lo = 0, hi = NEDGE;
  while (lo < hi) { int mid = (lo + hi) >> 1; if (adj_rows[mid] < r) lo = mid + 1; else hi = mid; }
  row_ptr[r] = lo;
}

// ---------- MFMA GEMM: C(MxN,f32) = A(MxK,bf16) * Bt(NxK,bf16)^T ----------
// 512 threads (8 waves, 2x4), 128x128 tile, per-wave 64x32 output.
__global__ __launch_bounds__(512) void k_gemm_bt(const u16* __restrict__ A,
                                                 const u16* __restrict__ Bt,
                                                 float* __restrict__ C,
                                                 int M, int N, int K) {
  __shared__ __align__(16) u16 As[128 * 32];
  __shared__ __align__(16) u16 Bs[128 * 32];
  const int ntx = N >> 7;
  const int bx = blockIdx.x % ntx;
  const int by = blockIdx.x / ntx;
  const int tid = threadIdx.x;
  const int wid = tid >> 6;
  const int lane = tid & 63;
  const int wr = wid >> 2, wc = wid & 3;  // 2x4 waves: each 64 rows x 32 cols
  const int rowbase = by * 128, colbase = bx * 128;

  f32x4 acc[4][2];
  #pragma unroll
  for (int i = 0; i < 4; ++i)
    #pragma unroll
    for (int j = 0; j < 2; ++j) acc[i][j] = (f32x4){0.f, 0.f, 0.f, 0.f};

  const int grow = tid >> 2;        // 0..127 source row
  const int gkk = (tid & 3) * 8;    // u16 offset within 32-wide k slab

  for (int kt = 0; kt < K; kt += 32) {
    {
      const u16* gA = A + (size_t)(rowbase + grow) * K + kt + gkk;
      __builtin_amdgcn_global_load_lds(
          (const __attribute__((address_space(1))) u32*)gA,
          (__attribute__((address_space(3))) u32*)(As + wid * 512), 16, 0, 0);
      const u16* gB = Bt + (size_t)(colbase + grow) * K + kt + gkk;
      __builtin_amdgcn_global_load_lds(
          (const __attribute__((address_space(1))) u32*)gB,
          (__attribute__((address_space(3))) u32*)(Bs + wid * 512), 16, 0, 0);
    }
    __syncthreads();  // drains vmcnt before LDS use
    bf16x8 af[4], bfr[2];
    #pragma unroll
    for (int mi = 0; mi < 4; ++mi) {
      int row = wr * 64 + mi * 16 + (lane & 15);
      af[mi] = *(const bf16x8*)(As + row * 32 + (lane >> 4) * 8);
    }
    #pragma unroll
    for (int ni = 0; ni < 2; ++ni) {
      int col = wc * 32 + ni * 16 + (lane & 15);
      bfr[ni] = *(const bf16x8*)(Bs + col * 32 + (lane >> 4) * 8);
    }
    #pragma unroll
    for (int mi = 0; mi < 4; ++mi)
      #pragma unroll
      for (int ni = 0; ni < 2; ++ni)
        acc[mi][ni] = __builtin_amdgcn_mfma_f32_16x16x32_bf16(af[mi], bfr[ni], acc[mi][ni], 0, 0, 0);
    __syncthreads();  // protect LDS before next iteration overwrites
  }

  #pragma unroll
  for (int mi = 0; mi < 4; ++mi) {
    #pragma unroll
    for (int ni = 0; ni < 2; ++ni) {
      int col = colbase + wc * 32 + ni * 16 + (lane & 15);
      #pragma unroll
      for (int j = 0; j < 4; ++j) {
        int row = rowbase + wr * 64 + mi * 16 + (lane >> 4) * 4 + j;
        C[(size_t)row * N + col] = acc[mi][ni][j];
      }
    }
  }
}

// ---------- SpMM (CSR) + bias + optional relu ----------
// Column-chunked (256 cols/block) so each XCD's L2 holds one X column-slice.
// chunks = width/256; blockIdx % chunks = chunk -> XCD round-robin alignment.
__global__ __launch_bounds__(256) void k_spmm(const float* __restrict__ X,
                                              const int* __restrict__ row_ptr,
                                              const int* __restrict__ adj_cols,
                                              const float* __restrict__ adj_vals,
                                              const float* __restrict__ bias,
                                              u16* __restrict__ Y16,
                                              float* __restrict__ Y32,
                                              int width, int do_relu) {
  int chunks = width >> 8;
  int ch = blockIdx.x % chunks;
  int r = blockIdx.x / chunks;
  int col = ch * 256 + threadIdx.x;
  int e0 = row_ptr[r], e1 = row_ptr[r + 1];
  float a = 0.f;
  for (int e = e0; e < e1; ++e) {
    int c = adj_cols[e] & (N_NODES - 1);
    a += adj_vals[e] * X[(size_t)c * width + col];
  }
  a += bias[col];
  if (do_relu) a = fmaxf(a, 0.f);
  if (Y16) Y16[(size_t)r * width + col] = f2bf(a);
  else     Y32[(size_t)r * width + col] = a;
}

// ---------- output assembly (all f32, streaming stores) ----------
__global__ __launch_bounds__(256) void k_assemble(const float* __restrict__ feat,
                                                  const float* __restrict__ logits,
                                                  const int* __restrict__ idx,
                                                  float* __restrict__ out) {
  int i = blockIdx.x;  // 0 .. B*7-1
  int b = i / 7, slot = i - b * 7;
  const float* src;
  if (slot == 0)      src = logits + (size_t)idx[7 * b + 1] * DIM;  // e2
  else if (slot == 1) src = logits + (size_t)idx[7 * b] * DIM;      // e1
  else                src = feat + ((size_t)b * 7 + slot) * DIM;
  f32x4 v = *(const f32x4*)(src + threadIdx.x * 4);
  __builtin_nontemporal_store(v, (f32x4*)(out + ((size_t)b * 7 + slot) * DIM + threadIdx.x * 4));
}

extern "C" void kernel_launch(void* const* d_in, const int* in_sizes, int n_in,
                              void* d_out, int out_size, void* d_ws, size_t ws_size,
                              hipStream_t stream) {
  const float* feat   = (const float*)d_in[0];
  const int* data_x   = (const int*)d_in[1];
  const int* adj_rows = (const int*)d_in[2];
  const int* adj_cols = (const int*)d_in[3];
  const float* adj_vals = (const float*)d_in[4];
  const float* W1 = (const float*)d_in[5];
  const float* b1 = (const float*)d_in[6];
  const float* W2 = (const float*)d_in[7];
  const float* b2 = (const float*)d_in[8];
  const float* W3 = (const float*)d_in[9];
  const float* b3 = (const float*)d_in[10];
  float* out = (float*)d_out;

  char* ws = (char*)d_ws;
  size_t off = 0;
  auto alloc = [&](size_t bytes) {
    char* p = ws + off; off += (bytes + 511) & ~(size_t)511; return p;
  };
  int*  flag    = (int*)alloc(4);
  int*  idx32   = (int*)alloc((size_t)7 * BATCH * 4);
  int*  counts  = (int*)alloc(N_NODES * 4);
  int*  bucket  = (int*)alloc((size_t)N_NODES * CAP * 4);
  int*  row_ptr = (int*)alloc((N_NODES + 1) * 4);
  u16*  A1      = (u16*)alloc((size_t)N_NODES * DIM * 2);        // 4 MB
  u16*  Wt      = (u16*)alloc((size_t)N_NODES * N_NODES * 2);    // 8 MB, reused per layer
  float* X      = (float*)alloc((size_t)N_NODES * N_NODES * 4);  // 16 MB, reused X1/X2/X3
  u16*  Hbuf    = (u16*)alloc((size_t)N_NODES * N_NODES * 2);    // 8 MB, H1 then H2
  float* logits = (float*)alloc((size_t)N_NODES * DIM * 4);      // 8 MB
  // peak ws use ~= 46 MB

  hipMemsetAsync(counts, 0, N_NODES * 4, stream);
  k_detect<<<1, 64, 0, stream>>>(data_x, flag);
  k_cvt<<<(7 * BATCH + 255) / 256, 256, 0, stream>>>(data_x, flag, idx32);
  k_bucket<<<(2 * BATCH + 255) / 256, 256, 0, stream>>>(idx32, counts, bucket);
  k_nodesum<<<N_NODES, 256, 0, stream>>>(feat, counts, bucket, A1);
  k_rowptr<<<N_NODES / 256 + 1, 256, 0, stream>>>(adj_rows, row_ptr);

  // layer 1: X = A1 @ W1 ; H1 = relu(spmm(X) + b1)
  k_transpose<<<(N_NODES / 32) * (DIM / 32), 256, 0, stream>>>(W1, Wt, DIM, N_NODES);
  k_gemm_bt<<<(N_NODES / 128) * (N_NODES / 128), 512, 0, stream>>>(A1, Wt, X, N_NODES, N_NODES, DIM);
  k_spmm<<<N_NODES * (N_NODES / 256), 256, 0, stream>>>(X, row_ptr, adj_cols, adj_vals, b1, Hbuf, nullptr, N_NODES, 1);
  // layer 2: X = H1 @ W2 ; H2 = spmm(X) + b2
  k_transpose<<<(N_NODES / 32) * (N_NODES / 32), 256, 0, stream>>>(W2, Wt, N_NODES, N_NODES);
  k_gemm_bt<<<(N_NODES / 128) * (N_NODES / 128), 512, 0, stream>>>(Hbuf, Wt, X, N_NODES, N_NODES, N_NODES);
  k_spmm<<<N_NODES * (N_NODES / 256), 256, 0, stream>>>(X, row_ptr, adj_cols, adj_vals, b2, Hbuf, nullptr, N_NODES, 0);
  // layer 3: X = H2 @ W3 ; logits = spmm(X) + b3 (f32 out)
  k_transpose<<<(DIM / 32) * (N_NODES / 32), 256, 0, stream>>>(W3, Wt, N_NODES, DIM);
  k_gemm_bt<<<(N_NODES / 128) * (DIM / 128), 512, 0, stream>>>(Hbuf, Wt, X, N_NODES, DIM, N_NODES);
  k_spmm<<<N_NODES * (DIM / 256), 256, 0, stream>>>(X, row_ptr, adj_cols, adj_vals, b3, nullptr, logits, DIM, 0);

  k_assemble<<<BATCH * 7, 256, 0, stream>>>(feat, logits, idx32, out);
}

// Round 5
// 354.081 us; speedup vs baseline: 1.3116x; 1.3116x over previous
//
#include <hip/hip_runtime.h>
#include <stdint.h>

#define N_NODES 2048
#define DIM 1024
#define BATCH 16384
#define NEDGE 65536
#define CAP 96

typedef __bf16 bf16x8 __attribute__((ext_vector_type(8)));
typedef float f32x4 __attribute__((ext_vector_type(4)));
typedef unsigned short u16;
typedef unsigned int u32;

__device__ __forceinline__ float bf2f(u16 u) {
  union { u32 i; float f; } v; v.i = ((u32)u) << 16; return v.f;
}
__device__ __forceinline__ u16 f2bf(float f) {
  union { float f; u32 i; } v; v.f = f;
  u32 r = v.i + 0x7fffu + ((v.i >> 16) & 1u);
  return (u16)(r >> 16);
}

// ---------- detect int64-vs-int32 index array + zero counts ----------
__global__ void k_detect(const int* __restrict__ dx, int* __restrict__ flag,
                         int* __restrict__ counts) {
  int t = threadIdx.x;
  for (int j = t; j < N_NODES; j += 64) counts[j] = 0;
  if (t == 0) {
    int is64 = 1;
    for (int j = 0; j < 32; ++j)
      if (dx[2 * j + 1] != 0) { is64 = 0; break; }
    *flag = is64;
  }
}

__global__ __launch_bounds__(256) void k_cvt(const int* __restrict__ dx,
                                             const int* __restrict__ flag,
                                             int* __restrict__ idx) {
  int i = blockIdx.x * 256 + threadIdx.x;
  if (i >= 7 * BATCH) return;
  int v = (*flag) ? dx[2 * i] : dx[i];
  idx[i] = v & (N_NODES - 1);
}

// ---------- bucket fill ----------
__global__ __launch_bounds__(256) void k_bucket(const int* __restrict__ idx,
                                                int* __restrict__ counts,
                                                int* __restrict__ bucket) {
  int i = blockIdx.x * 256 + threadIdx.x;
  if (i >= 2 * BATCH) return;
  int n = (i < BATCH) ? idx[7 * i] : idx[7 * (i - BATCH) + 1];
  int slot = atomicAdd(&counts[n], 1);
  if (slot < CAP) bucket[n * CAP + slot] = i;
}

// ---------- per-node segment sum (f32 in) -> A1 (bf16) ----------
__global__ __launch_bounds__(256) void k_nodesum(const float* __restrict__ feat,
                                                 const int* __restrict__ counts,
                                                 const int* __restrict__ bucket,
                                                 u16* __restrict__ A1) {
  int n = blockIdx.x;
  int tid = threadIdx.x;
  int cnt = counts[n]; if (cnt > CAP) cnt = CAP;
  float a0 = 0.f, a1 = 0.f, a2 = 0.f, a3 = 0.f;
  for (int j = 0; j < cnt; ++j) {
    int i = bucket[n * CAP + j];
    size_t rowoff = (i < BATCH) ? ((size_t)i * 7) * DIM
                                : ((size_t)(i - BATCH) * 7 + 1) * DIM;
    f32x4 v = *(const f32x4*)(feat + rowoff + tid * 4);
    a0 += v[0]; a1 += v[1]; a2 += v[2]; a3 += v[3];
  }
  ushort4 o; o.x = f2bf(a0); o.y = f2bf(a1); o.z = f2bf(a2); o.w = f2bf(a3);
  *(ushort4*)(A1 + (size_t)n * DIM + tid * 4) = o;
}

// ---------- weight transpose (K x N, f32) -> (N x K, bf16) ----------
__global__ __launch_bounds__(256) void k_transpose(const float* __restrict__ W,
                                                   u16* __restrict__ Wt,
                                                   int K, int N) {
  __shared__ __align__(16) u16 t[32][33];
  int ntx = N >> 5;
  int bx = blockIdx.x % ntx;
  int by = blockIdx.x / ntx;
  int tx = threadIdx.x & 31, ty = threadIdx.x >> 5;  // 32 x 8
  #pragma unroll
  for (int r = 0; r < 32; r += 8)
    t[r + ty][tx] = f2bf(W[(size_t)(by * 32 + r + ty) * N + bx * 32 + tx]);
  __syncthreads();
  #pragma unroll
  for (int r = 0; r < 32; r += 8)
    Wt[(size_t)(bx * 32 + r + ty) * K + by * 32 + tx] = t[tx][r + ty];
}

// ---------- CSR row_ptr via binary search over sorted adj_rows ----------
__global__ __launch_bounds__(256) void k_rowptr(const int* __restrict__ adj_rows,
                                                int* __restrict__ row_ptr) {
  int r = blockIdx.x * 256 + threadIdx.x;
  if (r > N_NODES) return;
  int lo = 0, hi = NEDGE;
  while (lo < hi) { int mid = (lo + hi) >> 1; if (adj_rows[mid] < r) lo = mid + 1; else hi = mid; }
  row_ptr[r] = lo;
}

// ---------- SpMM (CSR), bf16 X -> bf16 or f32(+bias) out, f32 accum ----------
__global__ __launch_bounds__(256) void k_spmm(const u16* __restrict__ X16,
                                              const int* __restrict__ row_ptr,
                                              const int* __restrict__ adj_cols,
                                              const float* __restrict__ adj_vals,
                                              const float* __restrict__ bias,  // null unless f32 out
                                              u16* __restrict__ Y16,
                                              float* __restrict__ Y32,
                                              int width) {
  int chunks = width >> 10;  // 1024 cols per block (4 per thread)
  int ch = blockIdx.x % chunks;
  int r = blockIdx.x / chunks;
  int col = ch * 1024 + threadIdx.x * 4;
  int e0 = row_ptr[r], e1 = row_ptr[r + 1];
  float a0 = 0.f, a1 = 0.f, a2 = 0.f, a3 = 0.f;
  for (int e = e0; e < e1; ++e) {
    int c = adj_cols[e] & (N_NODES - 1);
    float v = adj_vals[e];
    ushort4 x = *(const ushort4*)(X16 + (size_t)c * width + col);
    a0 += v * bf2f(x.x); a1 += v * bf2f(x.y);
    a2 += v * bf2f(x.z); a3 += v * bf2f(x.w);
  }
  if (Y16) {
    ushort4 o; o.x = f2bf(a0); o.y = f2bf(a1); o.z = f2bf(a2); o.w = f2bf(a3);
    *(ushort4*)(Y16 + (size_t)r * width + col) = o;
  } else {
    f32x4 bb = *(const f32x4*)(bias + col);
    f32x4 o; o[0] = a0 + bb[0]; o[1] = a1 + bb[1]; o[2] = a2 + bb[2]; o[3] = a3 + bb[3];
    *(f32x4*)(Y32 + (size_t)r * width + col) = o;
  }
}

// ---------- MFMA GEMM: C(MxN,bf16) = A(MxK,bf16) * Bt(NxK,bf16)^T ----------
// 256 threads, 4 waves (2x2). BM x BN tile; per-wave (BM/2)x(BN/2).
// Optional fused bias (f32) + relu in epilogue.
template <int BM, int BN, bool BIAS, bool RELU>
__global__ __launch_bounds__(256) void k_gemm(const u16* __restrict__ A,
                                              const u16* __restrict__ Bt,
                                              const float* __restrict__ bias,
                                              u16* __restrict__ C16,
                                              int M, int N, int K) {
  constexpr int WM = BM / 2, WN = BN / 2;
  constexpr int MI = WM / 16, NI = WN / 16;
  constexpr int IA = BM / 64, IB = BN / 64;  // staging issues (64 rows each)
  __shared__ __align__(16) u16 As[BM * 32];
  __shared__ __align__(16) u16 Bs[BN * 32];
  const int ntx = N / BN;
  const int bx = blockIdx.x % ntx;
  const int by = blockIdx.x / ntx;
  const int tid = threadIdx.x;
  const int wid = tid >> 6;
  const int lane = tid & 63;
  const int wr = wid >> 1, wc = wid & 1;
  const int rowbase = by * BM, colbase = bx * BN;

  f32x4 acc[MI][NI];
  #pragma unroll
  for (int i = 0; i < MI; ++i)
    #pragma unroll
    for (int j = 0; j < NI; ++j) acc[i][j] = (f32x4){0.f, 0.f, 0.f, 0.f};

  const int srow = wid * 16 + (lane >> 2);  // staging row within 64-row issue
  const int skk = (lane & 3) * 8;           // u16 k-offset

  for (int kt = 0; kt < K; kt += 32) {
    #pragma unroll
    for (int i = 0; i < IA; ++i) {
      const u16* g = A + (size_t)(rowbase + i * 64 + srow) * K + kt + skk;
      __builtin_amdgcn_global_load_lds(
          (const __attribute__((address_space(1))) u32*)g,
          (__attribute__((address_space(3))) u32*)(As + i * 2048 + wid * 512), 16, 0, 0);
    }
    #pragma unroll
    for (int i = 0; i < IB; ++i) {
      const u16* g = Bt + (size_t)(colbase + i * 64 + srow) * K + kt + skk;
      __builtin_amdgcn_global_load_lds(
          (const __attribute__((address_space(1))) u32*)g,
          (__attribute__((address_space(3))) u32*)(Bs + i * 2048 + wid * 512), 16, 0, 0);
    }
    __syncthreads();  // drains vmcnt before LDS use
    bf16x8 af[MI], bfr[NI];
    #pragma unroll
    for (int mi = 0; mi < MI; ++mi) {
      int row = wr * WM + mi * 16 + (lane & 15);
      af[mi] = *(const bf16x8*)(As + row * 32 + (lane >> 4) * 8);
    }
    #pragma unroll
    for (int ni = 0; ni < NI; ++ni) {
      int col = wc * WN + ni * 16 + (lane & 15);
      bfr[ni] = *(const bf16x8*)(Bs + col * 32 + (lane >> 4) * 8);
    }
    #pragma unroll
    for (int mi = 0; mi < MI; ++mi)
      #pragma unroll
      for (int ni = 0; ni < NI; ++ni)
        acc[mi][ni] = __builtin_amdgcn_mfma_f32_16x16x32_bf16(af[mi], bfr[ni], acc[mi][ni], 0, 0, 0);
    __syncthreads();  // protect LDS before next iteration overwrites
  }

  #pragma unroll
  for (int mi = 0; mi < MI; ++mi) {
    #pragma unroll
    for (int ni = 0; ni < NI; ++ni) {
      int col = colbase + wc * WN + ni * 16 + (lane & 15);
      float bv = BIAS ? bias[col] : 0.f;
      #pragma unroll
      for (int j = 0; j < 4; ++j) {
        int row = rowbase + wr * WM + mi * 16 + (lane >> 4) * 4 + j;
        float v = acc[mi][ni][j] + bv;
        if (RELU) v = fmaxf(v, 0.f);
        C16[(size_t)row * N + col] = f2bf(v);
      }
    }
  }
}

// ---------- output assembly (f32, streaming stores) ----------
__global__ __launch_bounds__(256) void k_assemble(const float* __restrict__ feat,
                                                  const float* __restrict__ logits,
                                                  const int* __restrict__ idx,
                                                  float* __restrict__ out) {
  int i = blockIdx.x;  // 0 .. B*7-1
  int b = i / 7, slot = i - b * 7;
  const float* src;
  if (slot == 0)      src = logits + (size_t)idx[7 * b + 1] * DIM;  // e2
  else if (slot == 1) src = logits + (size_t)idx[7 * b] * DIM;      // e1
  else                src = feat + ((size_t)b * 7 + slot) * DIM;
  f32x4 v = *(const f32x4*)(src + threadIdx.x * 4);
  __builtin_nontemporal_store(v, (f32x4*)(out + ((size_t)b * 7 + slot) * DIM + threadIdx.x * 4));
}

extern "C" void kernel_launch(void* const* d_in, const int* in_sizes, int n_in,
                              void* d_out, int out_size, void* d_ws, size_t ws_size,
                              hipStream_t stream) {
  const float* feat   = (const float*)d_in[0];
  const int* data_x   = (const int*)d_in[1];
  const int* adj_rows = (const int*)d_in[2];
  const int* adj_cols = (const int*)d_in[3];
  const float* adj_vals = (const float*)d_in[4];
  const float* W1 = (const float*)d_in[5];
  const float* b1 = (const float*)d_in[6];
  const float* W2 = (const float*)d_in[7];
  const float* b2 = (const float*)d_in[8];
  const float* W3 = (const float*)d_in[9];
  const float* b3 = (const float*)d_in[10];
  float* out = (float*)d_out;

  char* ws = (char*)d_ws;
  size_t off = 0;
  auto alloc = [&](size_t bytes) {
    char* p = ws + off; off += (bytes + 511) & ~(size_t)511; return p;
  };
  int*  flag    = (int*)alloc(4);
  int*  idx32   = (int*)alloc((size_t)7 * BATCH * 4);
  int*  counts  = (int*)alloc(N_NODES * 4);
  int*  bucket  = (int*)alloc((size_t)N_NODES * CAP * 4);
  int*  row_ptr = (int*)alloc((N_NODES + 1) * 4);
  u16*  A1      = (u16*)alloc((size_t)N_NODES * DIM * 2);        // 4 MB
  u16*  S       = (u16*)alloc((size_t)N_NODES * N_NODES * 2);    // 8 MB: S1, S2 (reused)
  u16*  H       = (u16*)alloc((size_t)N_NODES * N_NODES * 2);    // 8 MB: H1, H2 (reused)
  u16*  X3      = (u16*)alloc((size_t)N_NODES * DIM * 2);        // 4 MB
  u16*  Wt      = (u16*)alloc((size_t)N_NODES * N_NODES * 2);    // 8 MB, reused per layer
  float* logits = (float*)alloc((size_t)N_NODES * DIM * 4);      // 8 MB

  // prep
  k_detect<<<1, 64, 0, stream>>>(data_x, flag, counts);
  k_cvt<<<(7 * BATCH + 255) / 256, 256, 0, stream>>>(data_x, flag, idx32);
  k_bucket<<<(2 * BATCH + 255) / 256, 256, 0, stream>>>(idx32, counts, bucket);
  k_nodesum<<<N_NODES, 256, 0, stream>>>(feat, counts, bucket, A1);
  k_rowptr<<<N_NODES / 256 + 1, 256, 0, stream>>>(adj_rows, row_ptr);

  // layer 1: S1 = spmm(A1) [w=1024]; H1 = relu(S1 @ W1 + b1)
  k_transpose<<<(N_NODES / 32) * (DIM / 32), 256, 0, stream>>>(W1, Wt, DIM, N_NODES);
  k_spmm<<<N_NODES * (DIM / 1024), 256, 0, stream>>>(A1, row_ptr, adj_cols, adj_vals, nullptr, S, nullptr, DIM);
  k_gemm<128, 64, true, true><<<(N_NODES / 128) * (N_NODES / 64), 256, 0, stream>>>(S, Wt, b1, H, N_NODES, N_NODES, DIM);
  // layer 2: S2 = spmm(H1) [w=2048]; H2 = S2 @ W2 + b2
  k_transpose<<<(N_NODES / 32) * (N_NODES / 32), 256, 0, stream>>>(W2, Wt, N_NODES, N_NODES);
  k_spmm<<<N_NODES * (N_NODES / 1024), 256, 0, stream>>>(H, row_ptr, adj_cols, adj_vals, nullptr, S, nullptr, N_NODES);
  k_gemm<128, 64, true, false><<<(N_NODES / 128) * (N_NODES / 64), 256, 0, stream>>>(S, Wt, b2, H, N_NODES, N_NODES, N_NODES);
  // layer 3: X3 = H2 @ W3 ; logits = spmm(X3) + b3 [w=1024, f32 out]
  k_transpose<<<(DIM / 32) * (N_NODES / 32), 256, 0, stream>>>(W3, Wt, N_NODES, DIM);
  k_gemm<64, 64, false, false><<<(N_NODES / 64) * (DIM / 64), 256, 0, stream>>>(H, Wt, nullptr, X3, N_NODES, DIM, N_NODES);
  k_spmm<<<N_NODES * (DIM / 1024), 256, 0, stream>>>(X3, row_ptr, adj_cols, adj_vals, b3, nullptr, logits, DIM);

  k_assemble<<<BATCH * 7, 256, 0, stream>>>(feat, logits, idx32, out);
}

// Round 6
// 322.936 us; speedup vs baseline: 1.4381x; 1.0964x over previous
//
#include <hip/hip_runtime.h>
#include <stdint.h>

#define N_NODES 2048
#define DIM 1024
#define BATCH 16384
#define NEDGE 65536
#define CAP 96

typedef __bf16 bf16x8 __attribute__((ext_vector_type(8)));
typedef float f32x4 __attribute__((ext_vector_type(4)));
typedef unsigned short u16;
typedef unsigned int u32;

__device__ __forceinline__ float bf2f(u16 u) {
  union { u32 i; float f; } v; v.i = ((u32)u) << 16; return v.f;
}
__device__ __forceinline__ u16 f2bf(float f) {
  union { float f; u32 i; } v; v.f = f;
  u32 r = v.i + 0x7fffu + ((v.i >> 16) & 1u);
  return (u16)(r >> 16);
}

// ---------- detect int64-vs-int32 index array + zero counts ----------
__global__ void k_detect(const int* __restrict__ dx, int* __restrict__ flag,
                         int* __restrict__ counts) {
  int t = threadIdx.x;
  for (int j = t; j < N_NODES; j += 64) counts[j] = 0;
  if (t == 0) {
    int is64 = 1;
    for (int j = 0; j < 32; ++j)
      if (dx[2 * j + 1] != 0) { is64 = 0; break; }
    *flag = is64;
  }
}

// ---------- bucket fill (reads data_x directly, flag-aware) ----------
__global__ __launch_bounds__(256) void k_bucket(const int* __restrict__ dx,
                                                const int* __restrict__ flag,
                                                int* __restrict__ counts,
                                                int* __restrict__ bucket) {
  int i = blockIdx.x * 256 + threadIdx.x;
  if (i >= 2 * BATCH) return;
  int f = *flag;
  long p = (i < BATCH) ? 7L * i : 7L * (i - BATCH) + 1;
  int n = dx[f ? 2 * p : p] & (N_NODES - 1);
  int slot = atomicAdd(&counts[n], 1);
  if (slot < CAP) bucket[n * CAP + slot] = i;
}

// ---------- per-node segment sum (f32 in) -> A1 (bf16) ----------
__global__ __launch_bounds__(256) void k_nodesum(const float* __restrict__ feat,
                                                 const int* __restrict__ counts,
                                                 const int* __restrict__ bucket,
                                                 u16* __restrict__ A1) {
  int n = blockIdx.x;
  int tid = threadIdx.x;
  int cnt = counts[n]; if (cnt > CAP) cnt = CAP;
  float a0 = 0.f, a1 = 0.f, a2 = 0.f, a3 = 0.f;
  for (int j = 0; j < cnt; ++j) {
    int i = bucket[n * CAP + j];
    size_t rowoff = (i < BATCH) ? ((size_t)i * 7) * DIM
                                : ((size_t)(i - BATCH) * 7 + 1) * DIM;
    f32x4 v = *(const f32x4*)(feat + rowoff + tid * 4);
    a0 += v[0]; a1 += v[1]; a2 += v[2]; a3 += v[3];
  }
  ushort4 o; o.x = f2bf(a0); o.y = f2bf(a1); o.z = f2bf(a2); o.w = f2bf(a3);
  *(ushort4*)(A1 + (size_t)n * DIM + tid * 4) = o;
}

// ---------- weight transpose (K x N, f32) -> (N x K, bf16) ----------
__global__ __launch_bounds__(256) void k_transpose(const float* __restrict__ W,
                                                   u16* __restrict__ Wt,
                                                   int K, int N) {
  __shared__ __align__(16) u16 t[32][33];
  int ntx = N >> 5;
  int bx = blockIdx.x % ntx;
  int by = blockIdx.x / ntx;
  int tx = threadIdx.x & 31, ty = threadIdx.x >> 5;  // 32 x 8
  #pragma unroll
  for (int r = 0; r < 32; r += 8)
    t[r + ty][tx] = f2bf(W[(size_t)(by * 32 + r + ty) * N + bx * 32 + tx]);
  __syncthreads();
  #pragma unroll
  for (int r = 0; r < 32; r += 8)
    Wt[(size_t)(bx * 32 + r + ty) * K + by * 32 + tx] = t[tx][r + ty];
}

// ---------- CSR row_ptr via binary search over sorted adj_rows ----------
__global__ __launch_bounds__(256) void k_rowptr(const int* __restrict__ adj_rows,
                                                int* __restrict__ row_ptr) {
  int r = blockIdx.x * 256 + threadIdx.x;
  if (r > N_NODES) return;
  int lo = 0, hi = NEDGE;
  while (lo < hi) { int mid = (lo + hi) >> 1; if (adj_rows[mid] < r) lo = mid + 1; else hi = mid; }
  row_ptr[r] = lo;
}

// ---------- SpMM (CSR), bf16 X -> bf16 or f32(+bias) out, f32 accum ----------
__global__ __launch_bounds__(256) void k_spmm(const u16* __restrict__ X16,
                                              const int* __restrict__ row_ptr,
                                              const int* __restrict__ adj_cols,
                                              const float* __restrict__ adj_vals,
                                              const float* __restrict__ bias,  // null unless f32 out
                                              u16* __restrict__ Y16,
                                              float* __restrict__ Y32,
                                              int width) {
  int chunks = width >> 10;  // 1024 cols per block (4 per thread)
  int ch = blockIdx.x % chunks;
  int r = blockIdx.x / chunks;
  int col = ch * 1024 + threadIdx.x * 4;
  int e0 = row_ptr[r], e1 = row_ptr[r + 1];
  float a0 = 0.f, a1 = 0.f, a2 = 0.f, a3 = 0.f;
  int e = e0;
  for (; e + 2 <= e1; e += 2) {
    int c0 = adj_cols[e] & (N_NODES - 1);
    int c1 = adj_cols[e + 1] & (N_NODES - 1);
    float v0 = adj_vals[e], v1 = adj_vals[e + 1];
    ushort4 x0 = *(const ushort4*)(X16 + (size_t)c0 * width + col);
    ushort4 x1 = *(const ushort4*)(X16 + (size_t)c1 * width + col);
    a0 += v0 * bf2f(x0.x) + v1 * bf2f(x1.x);
    a1 += v0 * bf2f(x0.y) + v1 * bf2f(x1.y);
    a2 += v0 * bf2f(x0.z) + v1 * bf2f(x1.z);
    a3 += v0 * bf2f(x0.w) + v1 * bf2f(x1.w);
  }
  if (e < e1) {
    int c = adj_cols[e] & (N_NODES - 1);
    float v = adj_vals[e];
    ushort4 x = *(const ushort4*)(X16 + (size_t)c * width + col);
    a0 += v * bf2f(x.x); a1 += v * bf2f(x.y);
    a2 += v * bf2f(x.z); a3 += v * bf2f(x.w);
  }
  if (Y16) {
    ushort4 o; o.x = f2bf(a0); o.y = f2bf(a1); o.z = f2bf(a2); o.w = f2bf(a3);
    *(ushort4*)(Y16 + (size_t)r * width + col) = o;
  } else {
    f32x4 bb = *(const f32x4*)(bias + col);
    f32x4 o; o[0] = a0 + bb[0]; o[1] = a1 + bb[1]; o[2] = a2 + bb[2]; o[3] = a3 + bb[3];
    *(f32x4*)(Y32 + (size_t)r * width + col) = o;
  }
}

// ---------- MFMA GEMM, 2-phase double-buffered, BK=64, swizzled LDS ----------
// C(MxN,bf16) = A(MxK,bf16) * Bt(NxK,bf16)^T  [+bias, +relu]
// 256 threads, 4 waves (2x2), per-wave (BM/2)x(BN/2).
template <int BM, int BN, bool BIAS, bool RELU>
__global__ __launch_bounds__(256) void k_gemm(const u16* __restrict__ A,
                                              const u16* __restrict__ Bt,
                                              const float* __restrict__ bias,
                                              u16* __restrict__ C16,
                                              int M, int N, int K) {
  constexpr int BK = 64;                       // u16 elements per K-step
  constexpr int WM = BM / 2, WN = BN / 2;
  constexpr int MI = WM / 16, NI = WN / 16;
  constexpr int IA = BM / 32, IB = BN / 32;    // 32-row staging issues
  __shared__ __align__(16) u16 As[2][BM * BK];
  __shared__ __align__(16) u16 Bs[2][BN * BK];
  const int ntx = N / BN;
  const int bx = blockIdx.x % ntx;
  const int by = blockIdx.x / ntx;
  const int tid = threadIdx.x;
  const int wid = tid >> 6;
  const int lane = tid & 63;
  const int wr = wid >> 1, wc = wid & 1;
  const int rowbase = by * BM, colbase = bx * BN;

  f32x4 acc[MI][NI];
  #pragma unroll
  for (int i = 0; i < MI; ++i)
    #pragma unroll
    for (int j = 0; j < NI; ++j) acc[i][j] = (f32x4){0.f, 0.f, 0.f, 0.f};

  // staging: thread t covers row (t>>3) of each 32-row issue, 16B of k.
  // source k pre-swizzled so linear LDS dest + swizzled read match (rule 21).
  const int srow = tid >> 3;
  const int skk = (((tid & 7) ^ (srow & 7)) << 3);

  #define STAGE(buf, kt)                                                        \
    do {                                                                        \
      _Pragma("unroll")                                                         \
      for (int i = 0; i < IA; ++i) {                                            \
        const u16* g = A + (size_t)(rowbase + i * 32 + srow) * K + (kt) + skk;  \
        __builtin_amdgcn_global_load_lds(                                       \
            (const __attribute__((address_space(1))) u32*)g,                    \
            (__attribute__((address_space(3))) u32*)(&As[buf][i * 2048 + tid * 8]), \
            16, 0, 0);                                                          \
      }                                                                         \
      _Pragma("unroll")                                                         \
      for (int i = 0; i < IB; ++i) {                                            \
        const u16* g = Bt + (size_t)(colbase + i * 32 + srow) * K + (kt) + skk; \
        __builtin_amdgcn_global_load_lds(                                       \
            (const __attribute__((address_space(1))) u32*)g,                    \
            (__attribute__((address_space(3))) u32*)(&Bs[buf][i * 2048 + tid * 8]), \
            16, 0, 0);                                                          \
      }                                                                         \
    } while (0)

  const int rrow = lane & 15;
  const int kq = (lane >> 4) * 8;       // u16 offset within 32-wide k half
  const int rswz = (lane & 7) << 3;     // read-side XOR (row&7)

  const int nk = K >> 6;
  STAGE(0, 0);
  __syncthreads();  // vmcnt(0) drain + barrier: buf0 ready

  for (int t = 0; t < nk; ++t) {
    const u16* as = As[t & 1];
    const u16* bs = Bs[t & 1];
    if (t + 1 < nk) STAGE((t + 1) & 1, (t + 1) << 6);  // overlap with compute
    bf16x8 af[MI][2], bfr[NI][2];
    #pragma unroll
    for (int mi = 0; mi < MI; ++mi) {
      int r = wr * WM + mi * 16 + rrow;
      #pragma unroll
      for (int h = 0; h < 2; ++h)
        af[mi][h] = *(const bf16x8*)(as + r * 64 + ((h * 32 + kq) ^ rswz));
    }
    #pragma unroll
    for (int ni = 0; ni < NI; ++ni) {
      int c = wc * WN + ni * 16 + rrow;
      #pragma unroll
      for (int h = 0; h < 2; ++h)
        bfr[ni][h] = *(const bf16x8*)(bs + c * 64 + ((h * 32 + kq) ^ rswz));
    }
    #pragma unroll
    for (int h = 0; h < 2; ++h)
      #pragma unroll
      for (int mi = 0; mi < MI; ++mi)
        #pragma unroll
        for (int ni = 0; ni < NI; ++ni)
          acc[mi][ni] = __builtin_amdgcn_mfma_f32_16x16x32_bf16(af[mi][h], bfr[ni][h], acc[mi][ni], 0, 0, 0);
    __syncthreads();  // drains next-buf stage loads; all cur reads complete
  }
  #undef STAGE

  #pragma unroll
  for (int mi = 0; mi < MI; ++mi) {
    #pragma unroll
    for (int ni = 0; ni < NI; ++ni) {
      int col = colbase + wc * WN + ni * 16 + rrow;
      float bv = BIAS ? bias[col] : 0.f;
      #pragma unroll
      for (int j = 0; j < 4; ++j) {
        int row = rowbase + wr * WM + mi * 16 + (lane >> 4) * 4 + j;
        float v = acc[mi][ni][j] + bv;
        if (RELU) v = fmaxf(v, 0.f);
        C16[(size_t)row * N + col] = f2bf(v);
      }
    }
  }
}

// ---------- output assembly (f32, streaming stores, flag-aware) ----------
__global__ __launch_bounds__(256) void k_assemble(const float* __restrict__ feat,
                                                  const float* __restrict__ logits,
                                                  const int* __restrict__ dx,
                                                  const int* __restrict__ flag,
                                                  float* __restrict__ out) {
  int i = blockIdx.x;  // 0 .. B*7-1
  int b = i / 7, slot = i - b * 7;
  const float* src;
  if (slot <= 1) {
    int f = *flag;
    long p = 7L * b + (slot == 0 ? 1 : 0);  // slot0 -> e2, slot1 -> e1
    int node = dx[f ? 2 * p : p] & (N_NODES - 1);
    src = logits + (size_t)node * DIM;
  } else {
    src = feat + ((size_t)b * 7 + slot) * DIM;
  }
  f32x4 v = *(const f32x4*)(src + threadIdx.x * 4);
  __builtin_nontemporal_store(v, (f32x4*)(out + ((size_t)b * 7 + slot) * DIM + threadIdx.x * 4));
}

extern "C" void kernel_launch(void* const* d_in, const int* in_sizes, int n_in,
                              void* d_out, int out_size, void* d_ws, size_t ws_size,
                              hipStream_t stream) {
  const float* feat   = (const float*)d_in[0];
  const int* data_x   = (const int*)d_in[1];
  const int* adj_rows = (const int*)d_in[2];
  const int* adj_cols = (const int*)d_in[3];
  const float* adj_vals = (const float*)d_in[4];
  const float* W1 = (const float*)d_in[5];
  const float* b1 = (const float*)d_in[6];
  const float* W2 = (const float*)d_in[7];
  const float* b2 = (const float*)d_in[8];
  const float* W3 = (const float*)d_in[9];
  const float* b3 = (const float*)d_in[10];
  float* out = (float*)d_out;

  char* ws = (char*)d_ws;
  size_t off = 0;
  auto alloc = [&](size_t bytes) {
    char* p = ws + off; off += (bytes + 511) & ~(size_t)511; return p;
  };
  int*  flag    = (int*)alloc(4);
  int*  counts  = (int*)alloc(N_NODES * 4);
  int*  bucket  = (int*)alloc((size_t)N_NODES * CAP * 4);
  int*  row_ptr = (int*)alloc((N_NODES + 1) * 4);
  u16*  A1      = (u16*)alloc((size_t)N_NODES * DIM * 2);        // 4 MB
  u16*  S       = (u16*)alloc((size_t)N_NODES * N_NODES * 2);    // 8 MB: S1, S2
  u16*  H       = (u16*)alloc((size_t)N_NODES * N_NODES * 2);    // 8 MB: H1, H2
  u16*  X3      = (u16*)alloc((size_t)N_NODES * DIM * 2);        // 4 MB
  u16*  Wt      = (u16*)alloc((size_t)N_NODES * N_NODES * 2);    // 8 MB, per layer
  float* logits = (float*)alloc((size_t)N_NODES * DIM * 4);      // 8 MB

  // prep
  k_detect<<<1, 64, 0, stream>>>(data_x, flag, counts);
  k_bucket<<<(2 * BATCH + 255) / 256, 256, 0, stream>>>(data_x, flag, counts, bucket);
  k_nodesum<<<N_NODES, 256, 0, stream>>>(feat, counts, bucket, A1);
  k_rowptr<<<N_NODES / 256 + 1, 256, 0, stream>>>(adj_rows, row_ptr);

  // layer 1: S1 = spmm(A1) [w=1024]; H1 = relu(S1 @ W1 + b1)
  k_transpose<<<(N_NODES / 32) * (DIM / 32), 256, 0, stream>>>(W1, Wt, DIM, N_NODES);
  k_spmm<<<N_NODES * (DIM / 1024), 256, 0, stream>>>(A1, row_ptr, adj_cols, adj_vals, nullptr, S, nullptr, DIM);
  k_gemm<128, 64, true, true><<<(N_NODES / 128) * (N_NODES / 64), 256, 0, stream>>>(S, Wt, b1, H, N_NODES, N_NODES, DIM);
  // layer 2: S2 = spmm(H1) [w=2048]; H2 = S2 @ W2 + b2
  k_transpose<<<(N_NODES / 32) * (N_NODES / 32), 256, 0, stream>>>(W2, Wt, N_NODES, N_NODES);
  k_spmm<<<N_NODES * (N_NODES / 1024), 256, 0, stream>>>(H, row_ptr, adj_cols, adj_vals, nullptr, S, nullptr, N_NODES);
  k_gemm<128, 64, true, false><<<(N_NODES / 128) * (N_NODES / 64), 256, 0, stream>>>(S, Wt, b2, H, N_NODES, N_NODES, N_NODES);
  // layer 3: X3 = H2 @ W3 ; logits = spmm(X3) + b3 [w=1024, f32 out]
  k_transpose<<<(DIM / 32) * (N_NODES / 32), 256, 0, stream>>>(W3, Wt, N_NODES, DIM);
  k_gemm<64, 64, false, false><<<(N_NODES / 64) * (DIM / 64), 256, 0, stream>>>(H, Wt, nullptr, X3, N_NODES, DIM, N_NODES);
  k_spmm<<<N_NODES * (DIM / 1024), 256, 0, stream>>>(X3, row_ptr, adj_cols, adj_vals, b3, nullptr, logits, DIM);

  k_assemble<<<BATCH * 7, 256, 0, stream>>>(feat, logits, data_x, flag, out);
}